// Round 10
// baseline (630.351 us; speedup 1.0000x reference)
//
#include <hip/hip_runtime.h>
#include <stdint.h>

// Stage1Assigner (RPN matcher + subsample + top-k per GT) for MI355X.
// B=8 images, A=200000 anchors, G=64 GTs, K=4, thresholds 0.3/0.7, 128 max pos.
//
// PRNG: JAX threefry, jax_threefry_partitionable=True:
//   keys[b] = threefry2x32((0,42),(0,b));  bits[a] = y0^y1 of threefry2x32(key_b,(0,a))
// Selection of 128 positives = 128 lexicographically smallest (bits>>9, a).
//
// 4 dispatches:
//   k_top4_part  two-pass screened hot kernel (R8 bit-exact logic) with
//                `#pragma unroll 1` on the group loop — R8's spills (LDS +4KB,
//                1M bank conflicts, 26MB scratch writes) came from the compiler
//                unrolling both group bodies. s==0 blocks zero npos/fcnt/cnt.
//   k_top4_merge partials -> top4/hq; lq anchors atomicOr posA; stripe
//                popcount(posA|posB) -> npos (concurrent lq ORs only undercount
//                -> cutoff below only gets LARGER -> safe).
//   k_collect    cutoff C = 2^23*2048/max(npos,2048); positives with r23 < C
//                emit full 41-bit keys ((r23<<18)|a) into fine (cap 8192,
//                E[fcnt] in [1024,~2300] -> cap is >40 sigma). bx==0 zeroes tick.
//   k_count      per fine entry: exact global rank = #{fine keys < mine}
//                (keys >= C all have rank >= ~1024 >> 128 -> selection exact);
//                rank<128 -> argmax-gt (bit-identical IoU) -> cnt; ticket-last
//                block per image emits outputs (device-scope atomic cnt reads).
//
// IoU is fp-contract(off) IEEE per-op: identical bits across all passes and
// matches XLA per-HLO rounding. Workspace capped at the proven 2,025,536 B.

#pragma clang fp contract(off)

#define B_IMG 8
#define A_N 200000
#define G_N 64
#define K_TOP 4
#define MAX_POS 128
#define FINE_CAP 8192
#define AS 2048
#define NS 98            // ceil(200000/2048)
#define WPS 32           // u64 ballot words per slice
#define NWORD 3136       // NS*WPS words of pos bits per image
#define NB2 8            // k_count blocks per image

typedef unsigned long long u64;
typedef unsigned int u32;

__device__ __forceinline__ u32 rotl32(u32 v, int n) { return (v << n) | (v >> (32 - n)); }

__device__ __forceinline__ void tf_round(u32& x0, u32& x1, int r) {
  x0 += x1; x1 = rotl32(x1, r); x1 ^= x0;
}

__device__ __forceinline__ void threefry2x32(u32 k0, u32 k1, u32& x0, u32& x1) {
  u32 ks2 = 0x1BD11BDAu ^ k0 ^ k1;
  x0 += k0; x1 += k1;
  tf_round(x0,x1,13); tf_round(x0,x1,15); tf_round(x0,x1,26); tf_round(x0,x1,6);
  x0 += k1; x1 += ks2 + 1u;
  tf_round(x0,x1,17); tf_round(x0,x1,29); tf_round(x0,x1,16); tf_round(x0,x1,24);
  x0 += ks2; x1 += k0 + 2u;
  tf_round(x0,x1,13); tf_round(x0,x1,15); tf_round(x0,x1,26); tf_round(x0,x1,6);
  x0 += k0; x1 += k1 + 3u;
  tf_round(x0,x1,17); tf_round(x0,x1,29); tf_round(x0,x1,16); tf_round(x0,x1,24);
  x0 += k1; x1 += ks2 + 4u;
  tf_round(x0,x1,13); tf_round(x0,x1,15); tf_round(x0,x1,26); tf_round(x0,x1,6);
  x0 += ks2; x1 += k0 + 5u;
}

__device__ __forceinline__ void image_key(int b, u32& kb0, u32& kb1) {
  u32 x0 = 0u, x1 = (u32)b;
  threefry2x32(0u, 42u, x0, x1);
  kb0 = x0; kb1 = x1;
}

__device__ __forceinline__ u32 rbits_for(u32 k0, u32 k1, u32 a) {
  u32 x0 = 0u, x1 = a;
  threefry2x32(k0, k1, x0, x1);
  return x0 ^ x1;
}

__device__ __forceinline__ void conv_box(float4 bx, float& x0, float& y0,
                                         float& x1, float& y1, float& area) {
  #pragma clang fp contract(off)
  x0 = bx.x - 0.5f * bx.z;
  y0 = bx.y - 0.5f * bx.w;
  x1 = bx.x + 0.5f * bx.z;
  y1 = bx.y + 0.5f * bx.w;
  area = (x1 - x0) * (y1 - y0);
}

__device__ __forceinline__ float iou_pair(float ax0, float ay0, float ax1, float ay1, float aarea,
                                          float gx0, float gy0, float gx1, float gy1, float garea) {
  #pragma clang fp contract(off)
  float ltx = fmaxf(gx0, ax0), lty = fmaxf(gy0, ay0);
  float rbx = fminf(gx1, ax1), rby = fminf(gy1, ay1);
  float w = fmaxf(rbx - ltx, 0.0f), h = fmaxf(rby - lty, 0.0f);
  float inter = w * h;
  float uni = (garea + aarea) - inter;
  return inter / uni;
}

__device__ __forceinline__ void iou_parts(float ax0, float ay0, float ax1, float ay1, float aarea,
                                          float gx0, float gy0, float gx1, float gy1, float garea,
                                          float& inter, float& uni) {
  #pragma clang fp contract(off)
  float ltx = fmaxf(gx0, ax0), lty = fmaxf(gy0, ay0);
  float rbx = fminf(gx1, ax1), rby = fminf(gy1, ay1);
  float w = fmaxf(rbx - ltx, 0.0f), h = fmaxf(rby - lty, 0.0f);
  inter = w * h;
  uni = (garea + aarea) - inter;
}

__device__ __forceinline__ void top4_insert(u64 (&top)[4], u64 key) {
  if (key > top[3]) {
    if (key > top[0])      { top[3]=top[2]; top[2]=top[1]; top[1]=top[0]; top[0]=key; }
    else if (key > top[1]) { top[3]=top[2]; top[2]=top[1]; top[1]=key; }
    else if (key > top[2]) { top[3]=top[2]; top[2]=key; }
    else                   { top[3]=key; }
  }
}

__device__ __forceinline__ void wave_merge_top4(u64 (&top)[4]) {
  for (int off = 32; off >= 1; off >>= 1) {
    u64 o[4];
    #pragma unroll
    for (int k = 0; k < 4; k++) o[k] = __shfl_down(top[k], (unsigned)off);
    u64 m[4]; int i = 0, j = 0;
    #pragma unroll
    for (int k = 0; k < 4; k++) m[k] = (top[i] >= o[j]) ? top[i++] : o[j++];
    #pragma unroll
    for (int k = 0; k < 4; k++) top[k] = m[k];
  }
}

__device__ __forceinline__ void ins4_val(u32 (&h)[4], u32 v) {
  u32 t = v, mx, mn;
  mx = max(t, h[0]); mn = min(t, h[0]); h[0] = mx; t = mn;
  mx = max(t, h[1]); mn = min(t, h[1]); h[1] = mx; t = mn;
  mx = max(t, h[2]); mn = min(t, h[2]); h[2] = mx; t = mn;
  h[3] = max(t, h[3]);
}

__device__ __forceinline__ void wave_merge_top4_u32(u32 (&top)[4]) {
  for (int off = 32; off >= 1; off >>= 1) {
    u32 o[4];
    #pragma unroll
    for (int k = 0; k < 4; k++) o[k] = __shfl_down(top[k], (unsigned)off);
    u32 m[4]; int i = 0, j = 0;
    #pragma unroll
    for (int k = 0; k < 4; k++) m[k] = (top[i] >= o[j]) ? top[i++] : o[j++];
    #pragma unroll
    for (int k = 0; k < 4; k++) top[k] = m[k];
  }
}

__device__ __forceinline__ float screen_thresh(u32 tau) {
  u32 tb = (tau > 8u) ? (tau - 8u) : 0u;
  return __uint_as_float(tb);
}

// ---------------- Kernel 1: per-(slice, b, gt-half) top-4 + pos-bit ballot ----------------
__launch_bounds__(256, 4)
__global__ void k_top4_part(const float4* __restrict__ anchors, const float4* __restrict__ gt,
                            u64* __restrict__ partial,
                            u64* __restrict__ posA, u64* __restrict__ posB,
                            u32* __restrict__ npos, u32* __restrict__ fcnt,
                            u32* __restrict__ cnt) {
  const int s = blockIdx.x;
  const int b = blockIdx.y >> 1, half = blockIdx.y & 1;
  const int t = threadIdx.x;
  const int wave = t >> 6, lane = t & 63;

  __shared__ float4 sxy[AS];
  __shared__ float  sg[5][32];
  __shared__ u32    wm[256];

  if (s == 0 && half == 0) {        // zero small state (only ADDED to in later dispatches)
    if (t < 64) cnt[b * G_N + t] = 0;
    if (t == 0) { fcnt[b] = 0; npos[b] = 0; }
  }

  const int base = s * AS;
  const int acnt = min(AS, A_N - base);
  const float4* ab = anchors + (size_t)b * A_N + base;

  for (int j = t; j < acnt; j += 256) {
    float x0, y0, x1, y1, ar;
    conv_box(ab[j], x0, y0, x1, y1, ar);
    sxy[j] = make_float4(x0, y0, x1, y1);
  }
  if (t < 32) {
    float x0, y0, x1, y1, ar;
    conv_box(gt[(size_t)b * G_N + half * 32 + t], x0, y0, x1, y1, ar);
    sg[0][t] = x0; sg[1][t] = y0; sg[2][t] = x1; sg[3][t] = y1; sg[4][t] = ar;
  }
  __syncthreads();

  u32 m = 0;
  #pragma unroll 1                 // CRITICAL: R8 let both group bodies unroll -> spills
  for (int gp = wave; gp < 8; gp += 4) {
    const int gi = gp * 4;
    const float g0x0 = sg[0][gi],   g0y0 = sg[1][gi],   g0x1 = sg[2][gi],   g0y1 = sg[3][gi],   g0a = sg[4][gi];
    const float g1x0 = sg[0][gi+1], g1y0 = sg[1][gi+1], g1x1 = sg[2][gi+1], g1y1 = sg[3][gi+1], g1a = sg[4][gi+1];
    const float g2x0 = sg[0][gi+2], g2y0 = sg[1][gi+2], g2x1 = sg[2][gi+2], g2y1 = sg[3][gi+2], g2a = sg[4][gi+2];
    const float g3x0 = sg[0][gi+3], g3y0 = sg[1][gi+3], g3x1 = sg[2][gi+3], g3y1 = sg[3][gi+3], g3a = sg[4][gi+3];

    // ---- pass 1: approx per-gt top-4 values (no div, no index, no branch) ----
    u32 q0[4] = {0,0,0,0}, q1[4] = {0,0,0,0}, q2[4] = {0,0,0,0}, q3[4] = {0,0,0,0};
    for (int j = lane; j < acnt; j += 64) {
      float4 x = sxy[j];
      float aarea = (x.z - x.x) * (x.w - x.y);
      float i0, u0, i1, u1, i2, u2, i3, u3;
      iou_parts(x.x, x.y, x.z, x.w, aarea, g0x0, g0y0, g0x1, g0y1, g0a, i0, u0);
      iou_parts(x.x, x.y, x.z, x.w, aarea, g1x0, g1y0, g1x1, g1y1, g1a, i1, u1);
      iou_parts(x.x, x.y, x.z, x.w, aarea, g2x0, g2y0, g2x1, g2y1, g2a, i2, u2);
      iou_parts(x.x, x.y, x.z, x.w, aarea, g3x0, g3y0, g3x1, g3y1, g3a, i3, u3);
      ins4_val(q0, __float_as_uint(i0 * __builtin_amdgcn_rcpf(u0)));
      ins4_val(q1, __float_as_uint(i1 * __builtin_amdgcn_rcpf(u1)));
      ins4_val(q2, __float_as_uint(i2 * __builtin_amdgcn_rcpf(u2)));
      ins4_val(q3, __float_as_uint(i3 * __builtin_amdgcn_rcpf(u3)));
    }
    wave_merge_top4_u32(q0);
    wave_merge_top4_u32(q1);
    wave_merge_top4_u32(q2);
    wave_merge_top4_u32(q3);
    u32 Q40 = __shfl(q0[3], 0), Q41 = __shfl(q1[3], 0);
    u32 Q42 = __shfl(q2[3], 0), Q43 = __shfl(q3[3], 0);
    const u32 L7 = 0x3F333333u - 8u;   // 0.7f bits - 8 ulp
    float t0 = screen_thresh(min(Q40 > 16u ? Q40 - 16u : 0u, L7));
    float t1 = screen_thresh(min(Q41 > 16u ? Q41 - 16u : 0u, L7));
    float t2 = screen_thresh(min(Q42 > 16u ? Q42 - 16u : 0u, L7));
    float t3 = screen_thresh(min(Q43 > 16u ? Q43 - 16u : 0u, L7));

    // ---- pass 2: screened exact top-4 + >=0.7 bits ----
    u64 T0[4] = {0,0,0,0}, T1[4] = {0,0,0,0}, T2[4] = {0,0,0,0}, T3[4] = {0,0,0,0};
    u32 h0 = 0, h1 = 0, h2 = 0, h3 = 0;
    u32 bit = 1u;
    for (int j = lane; j < acnt; j += 64, bit <<= 1) {
      float4 x = sxy[j];
      float aarea = (x.z - x.x) * (x.w - x.y);
      float i0, u0, i1, u1, i2, u2, i3, u3;
      iou_parts(x.x, x.y, x.z, x.w, aarea, g0x0, g0y0, g0x1, g0y1, g0a, i0, u0);
      iou_parts(x.x, x.y, x.z, x.w, aarea, g1x0, g1y0, g1x1, g1y1, g1a, i1, u1);
      iou_parts(x.x, x.y, x.z, x.w, aarea, g2x0, g2y0, g2x1, g2y1, g2a, i2, u2);
      iou_parts(x.x, x.y, x.z, x.w, aarea, g3x0, g3y0, g3x1, g3y1, g3a, i3, u3);
      u32 ni = ~(u32)(base + j);
      bool s0 = (i0 >= t0 * u0), s1 = (i1 >= t1 * u1);
      bool s2 = (i2 >= t2 * u2), s3 = (i3 >= t3 * u3);
      if (__ballot(s0)) {
        float v = 0.0f;
        if (s0) { v = i0 / u0; if (v >= 0.7f) m |= bit; }
        u32 vb = __float_as_uint(v);
        bool ins = s0 && (vb >= h0);
        if (__ballot(ins)) {
          if (ins) top4_insert(T0, ((u64)vb << 32) | (u64)ni);
          h0 = (u32)(T0[3] >> 32);
        }
      }
      if (__ballot(s1)) {
        float v = 0.0f;
        if (s1) { v = i1 / u1; if (v >= 0.7f) m |= bit; }
        u32 vb = __float_as_uint(v);
        bool ins = s1 && (vb >= h1);
        if (__ballot(ins)) {
          if (ins) top4_insert(T1, ((u64)vb << 32) | (u64)ni);
          h1 = (u32)(T1[3] >> 32);
        }
      }
      if (__ballot(s2)) {
        float v = 0.0f;
        if (s2) { v = i2 / u2; if (v >= 0.7f) m |= bit; }
        u32 vb = __float_as_uint(v);
        bool ins = s2 && (vb >= h2);
        if (__ballot(ins)) {
          if (ins) top4_insert(T2, ((u64)vb << 32) | (u64)ni);
          h2 = (u32)(T2[3] >> 32);
        }
      }
      if (__ballot(s3)) {
        float v = 0.0f;
        if (s3) { v = i3 / u3; if (v >= 0.7f) m |= bit; }
        u32 vb = __float_as_uint(v);
        bool ins = s3 && (vb >= h3);
        if (__ballot(ins)) {
          if (ins) top4_insert(T3, ((u64)vb << 32) | (u64)ni);
          h3 = (u32)(T3[3] >> 32);
        }
      }
    }
    wave_merge_top4(T0);
    wave_merge_top4(T1);
    wave_merge_top4(T2);
    wave_merge_top4(T3);
    if (lane == 0) {
      const int g = half * 32 + gi;
      u64* dst = partial + (((size_t)b * NS + s) * G_N + g) * 4;
      #pragma unroll
      for (int k = 0; k < 4; k++) {
        dst[k] = T0[k]; dst[4 + k] = T1[k]; dst[8 + k] = T2[k]; dst[12 + k] = T3[k];
      }
    }
  }

  wm[t] = m;
  __syncthreads();
  if (wave == 0) {
    u32 mc = wm[lane] | wm[64 + lane] | wm[128 + lane] | wm[192 + lane];
    u64* posH = (half ? posB : posA) + (size_t)b * NWORD + s * WPS;
    for (int k = 0; k < WPS; k++) {
      u64 bal = __ballot((mc >> k) & 1u);
      if (lane == 0) posH[k] = bal;    // plain store — every word covered exactly once
    }
  }
}

// ---------------- Kernel 2: merge -> top4; stripe popcount -> npos; lq -> posA ----------------
__launch_bounds__(64)
__global__ void k_top4_merge(const u64* __restrict__ partial, u64* __restrict__ top4,
                             u64* __restrict__ posA, const u64* __restrict__ posB,
                             u32* __restrict__ npos) {
  const int b = blockIdx.y, g = blockIdx.x, lane = threadIdx.x;

  // stripe popcount of posA|posB -> npos estimate (concurrent lq ORs from other
  // blocks only undercount -> collect's cutoff only grows -> safe).
  {
    const int w0 = g * 49;               // 64 blocks * 49 = 3136 = NWORD
    u32 c = 0;
    if (lane < 49 && w0 + lane < NWORD) {
      u64 w = posA[(size_t)b * NWORD + w0 + lane] | posB[(size_t)b * NWORD + w0 + lane];
      c = (u32)__popcll(w);
    }
    #pragma unroll
    for (int off = 32; off >= 1; off >>= 1) c += __shfl_xor(c, off);
    if (lane == 0 && c) atomicAdd(&npos[b], c);
  }

  const u64* pb = partial + ((size_t)b * NS * G_N + g) * 4;
  u64 keys[7];                           // NS*4 = 392 -> <= 7 per lane
  int nk = 0;
  for (int i = lane; i < NS * 4; i += 64)
    keys[nk++] = pb[(size_t)(i >> 2) * (G_N * 4) + (i & 3)];
  u64 top[4] = {0ull, 0ull, 0ull, 0ull};
  for (int q = 0; q < nk; q++) top4_insert(top, keys[q]);
  wave_merge_top4(top);
  if (lane == 0) {
    u64* dst = top4 + ((size_t)b * G_N + g) * 4;
    #pragma unroll
    for (int k = 0; k < 4; k++) dst[k] = top[k];
  }
  u32 hqb = (u32)(__shfl(top[0], 0) >> 32);
  for (int q = 0; q < nk; q++) {
    u64 key = keys[q];
    u32 aidx = ~(u32)key;
    if ((u32)(key >> 32) == hqb && aidx < A_N)
      atomicOr(&posA[(size_t)b * NWORD + (aidx >> 6)], 1ull << (aidx & 63));
  }
}

// ---------------- Kernel 3: sampled-cutoff collection of candidate keys ----------------
// grid (NS, B). C = 2^23*2048/max(npos,2048); emit 41-bit keys (r23<<18)|a for r23<C.
__launch_bounds__(256)
__global__ void k_collect(const u64* __restrict__ posA, const u64* __restrict__ posB,
                          const u32* __restrict__ npos,
                          u64* __restrict__ fine, u32* __restrict__ fcnt,
                          u32* __restrict__ tick) {
  const int b = blockIdx.y;
  const int t = threadIdx.x;
  if (blockIdx.x == 0 && t == 0) tick[b] = 0;   // read/modified only by k_count

  const u32 np = max(npos[b], 2048u);
  const u32 C = (u32)((((u64)2048u) << 23) / np);   // np=2048 -> 2^23 (full range)

  u32 k0, k1; image_key(b, k0, k1);
  const int a0 = blockIdx.x * AS;
  const u64* pa = posA + (size_t)b * NWORD;
  const u64* pb = posB + (size_t)b * NWORD;
  for (int j = t; j < AS; j += 256) {
    int a = a0 + j;
    if (a >= A_N) break;
    if (!(((pa[a >> 6] | pb[a >> 6]) >> (a & 63)) & 1ull)) continue;
    u32 r23 = rbits_for(k0, k1, (u32)a) >> 9;
    if (r23 >= C) continue;
    u32 idx = atomicAdd(&fcnt[b], 1u);
    if (idx < FINE_CAP) fine[(size_t)b * FINE_CAP + idx] = (((u64)r23) << 18) | (u64)(u32)a;
  }
}

// ---------------- Kernel 4: exact rank selection + per-gt counts + output ----------------
// grid (NB2, B). Every positive with key >= C has global rank >= ~1024 >> 128,
// so rank within fine == exact global rank for all fine members.
__launch_bounds__(256)
__global__ void k_count(const float4* __restrict__ anchors, const float4* __restrict__ gt,
                        const u64* __restrict__ top4, const u64* __restrict__ fine,
                        const u32* __restrict__ fcnt, u32* __restrict__ cnt,
                        u32* __restrict__ tick, float* __restrict__ out, int sec) {
  const int b = blockIdx.y;
  const int t = threadIdx.x;
  __shared__ float sg[5][64];
  __shared__ u32 sdone;

  if (t < 64) {
    float x0, y0, x1, y1, ar;
    conv_box(gt[(size_t)b * G_N + t], x0, y0, x1, y1, ar);
    sg[0][t] = x0; sg[1][t] = y0; sg[2][t] = x1; sg[3][t] = y1; sg[4][t] = ar;
  }
  __syncthreads();

  const int m = min((int)fcnt[b], FINE_CAP);
  const u64* fb = fine + (size_t)b * FINE_CAP;
  const float4* ab = anchors + (size_t)b * A_N;

  for (int e = blockIdx.x * 256 + t; e < m; e += NB2 * 256) {
    u64 ke = fb[e];
    u32 rank = 0;
    for (int j = 0; j < m; j++) rank += (fb[j] < ke) ? 1u : 0u;
    if (rank < MAX_POS) {
      u32 a = (u32)(ke & 0x3FFFFu);
      float ax0, ay0, ax1, ay1, aar;
      conv_box(ab[a], ax0, ay0, ax1, ay1, aar);
      float bv = -1.0f; int g0 = 0;
      for (int g = 0; g < 64; g++) {
        float v = iou_pair(ax0, ay0, ax1, ay1, aar,
                           sg[0][g], sg[1][g], sg[2][g], sg[3][g], sg[4][g]);
        if (v > bv) { bv = v; g0 = g; }   // strict > = first max (jnp.argmax)
      }
      atomicAdd(&cnt[b * G_N + g0], 1u);
    }
  }

  // ticket: last block per image emits the outputs.
  __syncthreads();
  __threadfence();
  if (t == 0) sdone = atomicAdd(&tick[b], 1u);
  __syncthreads();
  if (sdone == NB2 - 1 && t < 64) {
    const int g = t;
    const u32 c = min(atomicAdd(&cnt[b * G_N + g], 0u), (u32)K_TOP);  // coherent read
    const u64* t4 = top4 + ((size_t)b * G_N + g) * 4;
    #pragma unroll
    for (int k = 0; k < 4; k++) {
      u64 key = t4[k];
      u32 fbits = (u32)(key >> 32);
      u32 aidx = ~(u32)key;
      bool valid = (u32)k < c;
      int o = b * (G_N * K_TOP) + g * K_TOP + k;
      out[0 * sec + o] = valid ? (float)aidx : -1.0f;             // pr_inds
      out[1 * sec + o] = valid ? (float)g : -1.0f;                // gt_inds
      out[2 * sec + o] = valid ? 1.0f : 0.0f;                     // valid mask
      out[3 * sec + o] = valid ? __uint_as_float(fbits) : 0.0f;   // topk ious
    }
  }
}

extern "C" void kernel_launch(void* const* d_in, const int* in_sizes, int n_in,
                              void* d_out, int out_size, void* d_ws, size_t ws_size,
                              hipStream_t stream) {
  const float4* anchors = (const float4*)d_in[0];  // [B, A, 4] cxcywh
  const float4* gt      = (const float4*)d_in[1];  // [B, G, 4] cxcywh
  float* out = (float*)d_out;                      // 4 x [B, G*K] concatenated

  // Layout — IDENTICAL EXTENT to the proven 2,025,536 B:
  //   top4    @ 0          (16,384)
  //   partial @ 16,384     (1,605,632) — dead after k_top4_merge; aliased by:
  //       fine @ 16,384      (8192*8*8 = 524,288)  [k_collect, post-merge]
  //       tick @ 540,672     (32)                  [zeroed by k_collect bx==0]
  //   posA    @ 1,622,016  (200,704)  [fully ballot-stored — no init]
  //   posB    @ 1,822,720  (200,704)  [fully ballot-stored — no init]
  //   small   @ 2,023,424  (2,112): npos(32) fcnt(32) cnt(2,048)
  //            [zeroed by k_top4_part s==0 blocks]
  char* ws = (char*)d_ws;
  u64*  top4    = (u64*)(ws);
  u64*  partial = (u64*)(ws + 16384);
  u64*  fine    = (u64*)(ws + 16384);
  u32*  tick    = (u32*)(ws + 540672);
  u64*  posA    = (u64*)(ws + 1622016);
  u64*  posB    = (u64*)(ws + 1822720);
  u32*  npos    = (u32*)(ws + 2023424);
  u32*  fcnt    = (u32*)(ws + 2023456);
  u32*  cnt     = (u32*)(ws + 2023488);

  int sec = out_size / 4;  // 2048 = B*G*K

  k_top4_part <<<dim3(NS, B_IMG * 2), 256, 0, stream>>>(anchors, gt, partial, posA, posB,
                                                        npos, fcnt, cnt);
  k_top4_merge<<<dim3(G_N, B_IMG), 64, 0, stream>>>(partial, top4, posA, posB, npos);
  k_collect   <<<dim3(NS, B_IMG), 256, 0, stream>>>(posA, posB, npos, fine, fcnt, tick);
  k_count     <<<dim3(NB2, B_IMG), 256, 0, stream>>>(anchors, gt, top4, fine, fcnt, cnt,
                                                     tick, out, sec);
}

// Round 11
// 604.010 us; speedup vs baseline: 1.0436x; 1.0436x over previous
//
#include <hip/hip_runtime.h>
#include <stdint.h>

// Stage1Assigner (RPN matcher + subsample + top-k per GT) for MI355X.
// B=8 images, A=200000 anchors, G=64 GTs, K=4, thresholds 0.3/0.7, 128 max pos.
//
// PRNG: JAX threefry, jax_threefry_partitionable=True:
//   keys[b] = threefry2x32((0,42),(0,b));  bits[a] = y0^y1 of threefry2x32(key_b,(0,a))
// Selection of 128 positives = 128 lexicographically smallest (bits>>9, a).
//
// 4 dispatches:
//   k_top4_part  R5/R7-proven ONE-PASS hot kernel (230us, VALU 82%): per-(slice,
//                gt-half) top-4 (u64 keys, 32-bit prefilter) + >=0.7 ballots ->
//                posA/posB plain stores. s==0 blocks zero npos/fcnt.
//                (R8/R9's two-pass screen: neutral + spills -> abandoned.)
//   k_top4_merge partials -> top4/hq; lq anchors (val==hq) atomicOr posA;
//                stripe popcount(posA|posB) -> npos (concurrent lq ORs only
//                undercount -> cutoff only grows -> safe).
//   k_collect    cutoff C = 2^23*2048/max(npos,2048); positives with r23 < C
//                emit 41-bit keys ((r23<<18)|a) to fine (cap 8192 = E+136sigma).
//   k_sel        1 block/image: exact 128th-smallest threshold via 41-step
//                binary search (global fine reads, LDS reduce) -- replaces
//                R9's O(m^2) latency-bound rank scan (the 400us regression);
//                argmax-gt recomputed ONLY for <=128 selected; LDS counts;
//                emit (pr, gt, valid, scores).
//
// IoU is fp-contract(off) IEEE per-op: identical bits across all passes and
// matches XLA per-HLO rounding. Workspace capped at the proven 2,025,536 B.

#pragma clang fp contract(off)

#define B_IMG 8
#define A_N 200000
#define G_N 64
#define K_TOP 4
#define MAX_POS 128
#define FINE_CAP 8192
#define AS 2048
#define NS 98            // ceil(200000/2048)
#define WPS 32           // u64 ballot words per slice
#define NWORD 3136       // NS*WPS words of pos bits per image

typedef unsigned long long u64;
typedef unsigned int u32;

__device__ __forceinline__ u32 rotl32(u32 v, int n) { return (v << n) | (v >> (32 - n)); }

__device__ __forceinline__ void tf_round(u32& x0, u32& x1, int r) {
  x0 += x1; x1 = rotl32(x1, r); x1 ^= x0;
}

__device__ __forceinline__ void threefry2x32(u32 k0, u32 k1, u32& x0, u32& x1) {
  u32 ks2 = 0x1BD11BDAu ^ k0 ^ k1;
  x0 += k0; x1 += k1;
  tf_round(x0,x1,13); tf_round(x0,x1,15); tf_round(x0,x1,26); tf_round(x0,x1,6);
  x0 += k1; x1 += ks2 + 1u;
  tf_round(x0,x1,17); tf_round(x0,x1,29); tf_round(x0,x1,16); tf_round(x0,x1,24);
  x0 += ks2; x1 += k0 + 2u;
  tf_round(x0,x1,13); tf_round(x0,x1,15); tf_round(x0,x1,26); tf_round(x0,x1,6);
  x0 += k0; x1 += k1 + 3u;
  tf_round(x0,x1,17); tf_round(x0,x1,29); tf_round(x0,x1,16); tf_round(x0,x1,24);
  x0 += k1; x1 += ks2 + 4u;
  tf_round(x0,x1,13); tf_round(x0,x1,15); tf_round(x0,x1,26); tf_round(x0,x1,6);
  x0 += ks2; x1 += k0 + 5u;
}

__device__ __forceinline__ void image_key(int b, u32& kb0, u32& kb1) {
  u32 x0 = 0u, x1 = (u32)b;
  threefry2x32(0u, 42u, x0, x1);
  kb0 = x0; kb1 = x1;
}

__device__ __forceinline__ u32 rbits_for(u32 k0, u32 k1, u32 a) {
  u32 x0 = 0u, x1 = a;
  threefry2x32(k0, k1, x0, x1);
  return x0 ^ x1;
}

__device__ __forceinline__ void conv_box(float4 bx, float& x0, float& y0,
                                         float& x1, float& y1, float& area) {
  #pragma clang fp contract(off)
  x0 = bx.x - 0.5f * bx.z;
  y0 = bx.y - 0.5f * bx.w;
  x1 = bx.x + 0.5f * bx.z;
  y1 = bx.y + 0.5f * bx.w;
  area = (x1 - x0) * (y1 - y0);
}

__device__ __forceinline__ float iou_pair(float ax0, float ay0, float ax1, float ay1, float aarea,
                                          float gx0, float gy0, float gx1, float gy1, float garea) {
  #pragma clang fp contract(off)
  float ltx = fmaxf(gx0, ax0), lty = fmaxf(gy0, ay0);
  float rbx = fminf(gx1, ax1), rby = fminf(gy1, ay1);
  float w = fmaxf(rbx - ltx, 0.0f), h = fmaxf(rby - lty, 0.0f);
  float inter = w * h;
  float uni = (garea + aarea) - inter;
  return inter / uni;
}

__device__ __forceinline__ void top4_insert(u64 (&top)[4], u64 key) {
  if (key > top[3]) {
    if (key > top[0])      { top[3]=top[2]; top[2]=top[1]; top[1]=top[0]; top[0]=key; }
    else if (key > top[1]) { top[3]=top[2]; top[2]=top[1]; top[1]=key; }
    else if (key > top[2]) { top[3]=top[2]; top[2]=key; }
    else                   { top[3]=key; }
  }
}

__device__ __forceinline__ void wave_merge_top4(u64 (&top)[4]) {
  for (int off = 32; off >= 1; off >>= 1) {
    u64 o[4];
    #pragma unroll
    for (int k = 0; k < 4; k++) o[k] = __shfl_down(top[k], (unsigned)off);
    u64 m[4]; int i = 0, j = 0;
    #pragma unroll
    for (int k = 0; k < 4; k++) m[k] = (top[i] >= o[j]) ? top[i++] : o[j++];
    #pragma unroll
    for (int k = 0; k < 4; k++) top[k] = m[k];
  }
}

// ---------------- Kernel 1: per-(slice, b, gt-half) top-4 + pos-bit ballot ----------------
// grid (NS, B*2); block 256 = 4 waves; wave w handles 4-gt groups {w, w+4} of its half.
// EXACT R5/R7 hot loop (proven 230us, no spills).
__launch_bounds__(256, 4)
__global__ void k_top4_part(const float4* __restrict__ anchors, const float4* __restrict__ gt,
                            u64* __restrict__ partial,
                            u64* __restrict__ posA, u64* __restrict__ posB,
                            u32* __restrict__ npos, u32* __restrict__ fcnt) {
  const int s = blockIdx.x;
  const int b = blockIdx.y >> 1, half = blockIdx.y & 1;
  const int t = threadIdx.x;
  const int wave = t >> 6, lane = t & 63;

  __shared__ float4 sxy[AS];        // converted xyxy (area recomputed inline)
  __shared__ float  sg[5][32];
  __shared__ u32    wm[256];

  if (s == 0 && half == 0 && t == 0) { npos[b] = 0; fcnt[b] = 0; }

  const int base = s * AS;
  const int acnt = min(AS, A_N - base);
  const float4* ab = anchors + (size_t)b * A_N + base;

  for (int j = t; j < acnt; j += 256) {
    float x0, y0, x1, y1, ar;
    conv_box(ab[j], x0, y0, x1, y1, ar);
    sxy[j] = make_float4(x0, y0, x1, y1);
  }
  if (t < 32) {
    float x0, y0, x1, y1, ar;
    conv_box(gt[(size_t)b * G_N + half * 32 + t], x0, y0, x1, y1, ar);
    sg[0][t] = x0; sg[1][t] = y0; sg[2][t] = x1; sg[3][t] = y1; sg[4][t] = ar;
  }
  __syncthreads();

  u32 m = 0;   // bit k: anchor base+64k+lane has iou>=0.7 vs any of this thread's gts
  for (int gp = wave; gp < 8; gp += 4) {
    const int gi = gp * 4;
    const float g0x0 = sg[0][gi],   g0y0 = sg[1][gi],   g0x1 = sg[2][gi],   g0y1 = sg[3][gi],   g0a = sg[4][gi];
    const float g1x0 = sg[0][gi+1], g1y0 = sg[1][gi+1], g1x1 = sg[2][gi+1], g1y1 = sg[3][gi+1], g1a = sg[4][gi+1];
    const float g2x0 = sg[0][gi+2], g2y0 = sg[1][gi+2], g2x1 = sg[2][gi+2], g2y1 = sg[3][gi+2], g2a = sg[4][gi+2];
    const float g3x0 = sg[0][gi+3], g3y0 = sg[1][gi+3], g3x1 = sg[2][gi+3], g3y1 = sg[3][gi+3], g3a = sg[4][gi+3];
    u64 t0[4] = {0,0,0,0}, t1[4] = {0,0,0,0}, t2[4] = {0,0,0,0}, t3[4] = {0,0,0,0};
    u32 h0 = 0, h1 = 0, h2 = 0, h3 = 0;
    u32 bit = 1u;
    for (int j = lane; j < acnt; j += 64, bit <<= 1) {
      float4 x = sxy[j];
      float aarea = (x.z - x.x) * (x.w - x.y);
      float v0 = iou_pair(x.x, x.y, x.z, x.w, aarea, g0x0, g0y0, g0x1, g0y1, g0a);
      float v1 = iou_pair(x.x, x.y, x.z, x.w, aarea, g1x0, g1y0, g1x1, g1y1, g1a);
      float v2 = iou_pair(x.x, x.y, x.z, x.w, aarea, g2x0, g2y0, g2x1, g2y1, g2a);
      float v3 = iou_pair(x.x, x.y, x.z, x.w, aarea, g3x0, g3y0, g3x1, g3y1, g3a);
      if (fmaxf(fmaxf(v0, v1), fmaxf(v2, v3)) >= 0.7f) m |= bit;
      u32 ni = ~(u32)(base + j);
      u32 vb0 = __float_as_uint(v0), vb1 = __float_as_uint(v1);
      u32 vb2 = __float_as_uint(v2), vb3 = __float_as_uint(v3);
      if (vb0 >= h0) { top4_insert(t0, ((u64)vb0 << 32) | (u64)ni); h0 = (u32)(t0[3] >> 32); }
      if (vb1 >= h1) { top4_insert(t1, ((u64)vb1 << 32) | (u64)ni); h1 = (u32)(t1[3] >> 32); }
      if (vb2 >= h2) { top4_insert(t2, ((u64)vb2 << 32) | (u64)ni); h2 = (u32)(t2[3] >> 32); }
      if (vb3 >= h3) { top4_insert(t3, ((u64)vb3 << 32) | (u64)ni); h3 = (u32)(t3[3] >> 32); }
    }
    wave_merge_top4(t0);
    wave_merge_top4(t1);
    wave_merge_top4(t2);
    wave_merge_top4(t3);
    if (lane == 0) {
      const int g = half * 32 + gi;
      u64* dst = partial + (((size_t)b * NS + s) * G_N + g) * 4;
      #pragma unroll
      for (int k = 0; k < 4; k++) {
        dst[k] = t0[k]; dst[4 + k] = t1[k]; dst[8 + k] = t2[k]; dst[12 + k] = t3[k];
      }
    }
  }

  wm[t] = m;
  __syncthreads();
  if (wave == 0) {
    u32 mc = wm[lane] | wm[64 + lane] | wm[128 + lane] | wm[192 + lane];
    u64* posH = (half ? posB : posA) + (size_t)b * NWORD + s * WPS;
    for (int k = 0; k < WPS; k++) {
      u64 bal = __ballot((mc >> k) & 1u);
      if (lane == 0) posH[k] = bal;    // plain store — every word covered exactly once
    }
  }
}

// ---------------- Kernel 2: merge -> top4; stripe popcount -> npos; lq -> posA ----------------
__launch_bounds__(64)
__global__ void k_top4_merge(const u64* __restrict__ partial, u64* __restrict__ top4,
                             u64* __restrict__ posA, const u64* __restrict__ posB,
                             u32* __restrict__ npos) {
  const int b = blockIdx.y, g = blockIdx.x, lane = threadIdx.x;

  // stripe popcount of posA|posB -> npos estimate (concurrent lq ORs from other
  // blocks only undercount -> collect's cutoff only grows -> safe).
  {
    const int w0 = g * 49;               // 64 blocks * 49 = 3136 = NWORD
    u32 c = 0;
    if (lane < 49 && w0 + lane < NWORD) {
      u64 w = posA[(size_t)b * NWORD + w0 + lane] | posB[(size_t)b * NWORD + w0 + lane];
      c = (u32)__popcll(w);
    }
    #pragma unroll
    for (int off = 32; off >= 1; off >>= 1) c += __shfl_xor(c, off);
    if (lane == 0 && c) atomicAdd(&npos[b], c);
  }

  const u64* pb = partial + ((size_t)b * NS * G_N + g) * 4;
  u64 keys[7];                           // NS*4 = 392 -> <= 7 per lane
  int nk = 0;
  for (int i = lane; i < NS * 4; i += 64)
    keys[nk++] = pb[(size_t)(i >> 2) * (G_N * 4) + (i & 3)];
  u64 top[4] = {0ull, 0ull, 0ull, 0ull};
  for (int q = 0; q < nk; q++) top4_insert(top, keys[q]);
  wave_merge_top4(top);
  if (lane == 0) {
    u64* dst = top4 + ((size_t)b * G_N + g) * 4;
    #pragma unroll
    for (int k = 0; k < 4; k++) dst[k] = top[k];
  }
  // low-quality matches: every partial entry whose value bits == hq bits.
  u32 hqb = (u32)(__shfl(top[0], 0) >> 32);
  for (int q = 0; q < nk; q++) {
    u64 key = keys[q];
    u32 aidx = ~(u32)key;
    if ((u32)(key >> 32) == hqb && aidx < A_N)
      atomicOr(&posA[(size_t)b * NWORD + (aidx >> 6)], 1ull << (aidx & 63));
  }
}

// ---------------- Kernel 3: sampled-cutoff collection of candidate keys ----------------
// grid (NS, B). C = 2^23*2048/max(npos,2048); emit 41-bit keys (r23<<18)|a for r23<C.
// All keys of global rank <= ~2048 are collected (>> 128 needed) -> selection exact.
__launch_bounds__(256)
__global__ void k_collect(const u64* __restrict__ posA, const u64* __restrict__ posB,
                          const u32* __restrict__ npos,
                          u64* __restrict__ fine, u32* __restrict__ fcnt) {
  const int b = blockIdx.y;
  const int t = threadIdx.x;

  const u32 np = max(npos[b], 2048u);
  const u32 C = (u32)((((u64)2048u) << 23) / np);   // np=2048 -> 2^23 (keep all)

  u32 k0, k1; image_key(b, k0, k1);
  const int a0 = blockIdx.x * AS;
  const u64* pa = posA + (size_t)b * NWORD;
  const u64* pb = posB + (size_t)b * NWORD;
  for (int j = t; j < AS; j += 256) {
    int a = a0 + j;
    if (a >= A_N) break;
    if (!(((pa[a >> 6] | pb[a >> 6]) >> (a & 63)) & 1ull)) continue;
    u32 r23 = rbits_for(k0, k1, (u32)a) >> 9;
    if (r23 >= C) continue;
    u32 idx = atomicAdd(&fcnt[b], 1u);
    if (idx < FINE_CAP) fine[(size_t)b * FINE_CAP + idx] = (((u64)r23) << 18) | (u64)(u32)a;
  }
}

// ---------------- Kernel 4: threshold + per-gt counts + output (1 block/image) ----------------
__launch_bounds__(256)
__global__ void k_sel(const float4* __restrict__ anchors, const float4* __restrict__ gt,
                      const u64* __restrict__ top4, const u64* __restrict__ fine,
                      const u32* __restrict__ fcnt, float* __restrict__ out, int sec) {
  const int b = blockIdx.x;
  const int t = threadIdx.x;
  __shared__ float sg[5][64];
  __shared__ u32 red[256];
  __shared__ u32 scnt[64];
  __shared__ u64 sT;

  if (t < 64) {
    float x0, y0, x1, y1, ar;
    conv_box(gt[(size_t)b * G_N + t], x0, y0, x1, y1, ar);
    sg[0][t] = x0; sg[1][t] = y0; sg[2][t] = x1; sg[3][t] = y1; sg[4][t] = ar;
    scnt[t] = 0;
  }
  __syncthreads();

  const int m = min((int)fcnt[b], FINE_CAP);
  const u64* fb = fine + (size_t)b * FINE_CAP;

  // exact 128th-smallest threshold over the fine list (keys distinct)
  if (m > MAX_POS) {
    u64 lo = 0, hi = ((u64)1 << 41) - 1;
    while (lo < hi) {
      u64 mid = lo + ((hi - lo) >> 1);
      u32 c = 0;
      for (int j = t; j < m; j += 256) c += (fb[j] <= mid) ? 1u : 0u;
      red[t] = c;
      __syncthreads();
      for (int s = 128; s > 0; s >>= 1) { if (t < s) red[t] += red[t + s]; __syncthreads(); }
      c = red[0];
      __syncthreads();
      if (c >= MAX_POS) hi = mid; else lo = mid + 1;   // uniform
    }
    if (t == 0) sT = lo;
  } else if (t == 0) sT = ~0ull;
  __syncthreads();

  // argmax-gt for each selected anchor (<=128), LDS counts
  const u64 T = sT;
  const float4* ab = anchors + (size_t)b * A_N;
  for (int e = t; e < m; e += 256) {
    u64 ke = fb[e];
    if (ke > T) continue;
    u32 a = (u32)(ke & 0x3FFFFu);
    float ax0, ay0, ax1, ay1, aar;
    conv_box(ab[a], ax0, ay0, ax1, ay1, aar);
    float bv = -1.0f; int g0 = 0;
    for (int g = 0; g < 64; g++) {
      float v = iou_pair(ax0, ay0, ax1, ay1, aar,
                         sg[0][g], sg[1][g], sg[2][g], sg[3][g], sg[4][g]);
      if (v > bv) { bv = v; g0 = g; }   // strict > = first max (jnp.argmax)
    }
    atomicAdd(&scnt[g0], 1u);
  }
  __syncthreads();

  if (t < 64) {
    const int g = t;
    const u32 c = min(scnt[g], (u32)K_TOP);
    const u64* t4 = top4 + ((size_t)b * G_N + g) * 4;
    #pragma unroll
    for (int k = 0; k < 4; k++) {
      u64 key = t4[k];
      u32 fbits = (u32)(key >> 32);
      u32 aidx = ~(u32)key;
      bool valid = (u32)k < c;
      int o = b * (G_N * K_TOP) + g * K_TOP + k;
      out[0 * sec + o] = valid ? (float)aidx : -1.0f;             // pr_inds
      out[1 * sec + o] = valid ? (float)g : -1.0f;                // gt_inds
      out[2 * sec + o] = valid ? 1.0f : 0.0f;                     // valid mask
      out[3 * sec + o] = valid ? __uint_as_float(fbits) : 0.0f;   // topk ious
    }
  }
}

extern "C" void kernel_launch(void* const* d_in, const int* in_sizes, int n_in,
                              void* d_out, int out_size, void* d_ws, size_t ws_size,
                              hipStream_t stream) {
  const float4* anchors = (const float4*)d_in[0];  // [B, A, 4] cxcywh
  const float4* gt      = (const float4*)d_in[1];  // [B, G, 4] cxcywh
  float* out = (float*)d_out;                      // 4 x [B, G*K] concatenated

  // Layout — IDENTICAL EXTENT to the proven 2,025,536 B:
  //   top4    @ 0          (16,384)
  //   partial @ 16,384     (1,605,632) — dead after k_top4_merge; aliased by:
  //       fine @ 16,384      (8192*8*8 = 524,288)  [k_collect, post-merge]
  //   posA    @ 1,622,016  (200,704)  [fully ballot-stored — no init]
  //   posB    @ 1,822,720  (200,704)  [fully ballot-stored — no init]
  //   small   @ 2,023,424  (64): npos(32) fcnt(32) [zeroed by k_top4_part s==0]
  char* ws = (char*)d_ws;
  u64*  top4    = (u64*)(ws);
  u64*  partial = (u64*)(ws + 16384);
  u64*  fine    = (u64*)(ws + 16384);
  u64*  posA    = (u64*)(ws + 1622016);
  u64*  posB    = (u64*)(ws + 1822720);
  u32*  npos    = (u32*)(ws + 2023424);
  u32*  fcnt    = (u32*)(ws + 2023456);

  int sec = out_size / 4;  // 2048 = B*G*K

  k_top4_part <<<dim3(NS, B_IMG * 2), 256, 0, stream>>>(anchors, gt, partial, posA, posB,
                                                        npos, fcnt);
  k_top4_merge<<<dim3(G_N, B_IMG), 64, 0, stream>>>(partial, top4, posA, posB, npos);
  k_collect   <<<dim3(NS, B_IMG), 256, 0, stream>>>(posA, posB, npos, fine, fcnt);
  k_sel       <<<dim3(B_IMG), 256, 0, stream>>>(anchors, gt, top4, fine, fcnt, out, sec);
}

// Round 12
// 477.465 us; speedup vs baseline: 1.3202x; 1.2650x over previous
//
#include <hip/hip_runtime.h>
#include <stdint.h>

// Stage1Assigner (RPN matcher + subsample + top-k per GT) for MI355X.
// B=8 images, A=200000 anchors, G=64 GTs, K=4, thresholds 0.3/0.7, 128 max pos.
//
// PRNG: JAX threefry, jax_threefry_partitionable=True:
//   keys[b] = threefry2x32((0,42),(0,b));  bits[a] = y0^y1 of threefry2x32(key_b,(0,a))
// Selection of 128 positives = 128 lexicographically smallest (bits>>9, a).
//
// 4 dispatches:
//   k_top4_part  R5/R7-proven ONE-PASS hot kernel (231us, VALU 82%).
//   k_top4_merge partials -> top4/hq; lq anchors atomicOr posA; stripe
//                popcount -> npos (undercount-only -> cutoff grows -> safe).
//   k_collect    cutoff C = 2^23*2048/max(npos,2048); LDS-AGGREGATED emission:
//                per-block LDS buffer + ONE atomicAdd(&fcnt[b], cnt) range
//                reservation. R10/R11's per-candidate fetch-adds (~16K to one
//                cacheline from 8 XCDs) were the ~300us tail whale.
//   k_sel        1 block/image: exact 128th-smallest threshold (41-step binary
//                search, order-invariant); argmax-gt recompute for <=128
//                selected; LDS counts; emit outputs.
//
// IoU is fp-contract(off) IEEE per-op: identical bits across all passes and
// matches XLA per-HLO rounding. Workspace capped at the proven 2,025,536 B.

#pragma clang fp contract(off)

#define B_IMG 8
#define A_N 200000
#define G_N 64
#define K_TOP 4
#define MAX_POS 128
#define FINE_CAP 8192
#define LCAP 512         // per-block LDS candidate cap (~25x expected 21)
#define AS 2048
#define NS 98            // ceil(200000/2048)
#define WPS 32           // u64 ballot words per slice
#define NWORD 3136       // NS*WPS words of pos bits per image

typedef unsigned long long u64;
typedef unsigned int u32;

__device__ __forceinline__ u32 rotl32(u32 v, int n) { return (v << n) | (v >> (32 - n)); }

__device__ __forceinline__ void tf_round(u32& x0, u32& x1, int r) {
  x0 += x1; x1 = rotl32(x1, r); x1 ^= x0;
}

__device__ __forceinline__ void threefry2x32(u32 k0, u32 k1, u32& x0, u32& x1) {
  u32 ks2 = 0x1BD11BDAu ^ k0 ^ k1;
  x0 += k0; x1 += k1;
  tf_round(x0,x1,13); tf_round(x0,x1,15); tf_round(x0,x1,26); tf_round(x0,x1,6);
  x0 += k1; x1 += ks2 + 1u;
  tf_round(x0,x1,17); tf_round(x0,x1,29); tf_round(x0,x1,16); tf_round(x0,x1,24);
  x0 += ks2; x1 += k0 + 2u;
  tf_round(x0,x1,13); tf_round(x0,x1,15); tf_round(x0,x1,26); tf_round(x0,x1,6);
  x0 += k0; x1 += k1 + 3u;
  tf_round(x0,x1,17); tf_round(x0,x1,29); tf_round(x0,x1,16); tf_round(x0,x1,24);
  x0 += k1; x1 += ks2 + 4u;
  tf_round(x0,x1,13); tf_round(x0,x1,15); tf_round(x0,x1,26); tf_round(x0,x1,6);
  x0 += ks2; x1 += k0 + 5u;
}

__device__ __forceinline__ void image_key(int b, u32& kb0, u32& kb1) {
  u32 x0 = 0u, x1 = (u32)b;
  threefry2x32(0u, 42u, x0, x1);
  kb0 = x0; kb1 = x1;
}

__device__ __forceinline__ u32 rbits_for(u32 k0, u32 k1, u32 a) {
  u32 x0 = 0u, x1 = a;
  threefry2x32(k0, k1, x0, x1);
  return x0 ^ x1;
}

__device__ __forceinline__ void conv_box(float4 bx, float& x0, float& y0,
                                         float& x1, float& y1, float& area) {
  #pragma clang fp contract(off)
  x0 = bx.x - 0.5f * bx.z;
  y0 = bx.y - 0.5f * bx.w;
  x1 = bx.x + 0.5f * bx.z;
  y1 = bx.y + 0.5f * bx.w;
  area = (x1 - x0) * (y1 - y0);
}

__device__ __forceinline__ float iou_pair(float ax0, float ay0, float ax1, float ay1, float aarea,
                                          float gx0, float gy0, float gx1, float gy1, float garea) {
  #pragma clang fp contract(off)
  float ltx = fmaxf(gx0, ax0), lty = fmaxf(gy0, ay0);
  float rbx = fminf(gx1, ax1), rby = fminf(gy1, ay1);
  float w = fmaxf(rbx - ltx, 0.0f), h = fmaxf(rby - lty, 0.0f);
  float inter = w * h;
  float uni = (garea + aarea) - inter;
  return inter / uni;
}

__device__ __forceinline__ void top4_insert(u64 (&top)[4], u64 key) {
  if (key > top[3]) {
    if (key > top[0])      { top[3]=top[2]; top[2]=top[1]; top[1]=top[0]; top[0]=key; }
    else if (key > top[1]) { top[3]=top[2]; top[2]=top[1]; top[1]=key; }
    else if (key > top[2]) { top[3]=top[2]; top[2]=key; }
    else                   { top[3]=key; }
  }
}

__device__ __forceinline__ void wave_merge_top4(u64 (&top)[4]) {
  for (int off = 32; off >= 1; off >>= 1) {
    u64 o[4];
    #pragma unroll
    for (int k = 0; k < 4; k++) o[k] = __shfl_down(top[k], (unsigned)off);
    u64 m[4]; int i = 0, j = 0;
    #pragma unroll
    for (int k = 0; k < 4; k++) m[k] = (top[i] >= o[j]) ? top[i++] : o[j++];
    #pragma unroll
    for (int k = 0; k < 4; k++) top[k] = m[k];
  }
}

// ---------------- Kernel 1: per-(slice, b, gt-half) top-4 + pos-bit ballot ----------------
// EXACT R5/R7/R11 hot loop (proven 231us, no spills). FROZEN.
__launch_bounds__(256, 4)
__global__ void k_top4_part(const float4* __restrict__ anchors, const float4* __restrict__ gt,
                            u64* __restrict__ partial,
                            u64* __restrict__ posA, u64* __restrict__ posB,
                            u32* __restrict__ npos, u32* __restrict__ fcnt) {
  const int s = blockIdx.x;
  const int b = blockIdx.y >> 1, half = blockIdx.y & 1;
  const int t = threadIdx.x;
  const int wave = t >> 6, lane = t & 63;

  __shared__ float4 sxy[AS];        // converted xyxy (area recomputed inline)
  __shared__ float  sg[5][32];
  __shared__ u32    wm[256];

  if (s == 0 && half == 0 && t == 0) { npos[b] = 0; fcnt[b] = 0; }

  const int base = s * AS;
  const int acnt = min(AS, A_N - base);
  const float4* ab = anchors + (size_t)b * A_N + base;

  for (int j = t; j < acnt; j += 256) {
    float x0, y0, x1, y1, ar;
    conv_box(ab[j], x0, y0, x1, y1, ar);
    sxy[j] = make_float4(x0, y0, x1, y1);
  }
  if (t < 32) {
    float x0, y0, x1, y1, ar;
    conv_box(gt[(size_t)b * G_N + half * 32 + t], x0, y0, x1, y1, ar);
    sg[0][t] = x0; sg[1][t] = y0; sg[2][t] = x1; sg[3][t] = y1; sg[4][t] = ar;
  }
  __syncthreads();

  u32 m = 0;   // bit k: anchor base+64k+lane has iou>=0.7 vs any of this thread's gts
  for (int gp = wave; gp < 8; gp += 4) {
    const int gi = gp * 4;
    const float g0x0 = sg[0][gi],   g0y0 = sg[1][gi],   g0x1 = sg[2][gi],   g0y1 = sg[3][gi],   g0a = sg[4][gi];
    const float g1x0 = sg[0][gi+1], g1y0 = sg[1][gi+1], g1x1 = sg[2][gi+1], g1y1 = sg[3][gi+1], g1a = sg[4][gi+1];
    const float g2x0 = sg[0][gi+2], g2y0 = sg[1][gi+2], g2x1 = sg[2][gi+2], g2y1 = sg[3][gi+2], g2a = sg[4][gi+2];
    const float g3x0 = sg[0][gi+3], g3y0 = sg[1][gi+3], g3x1 = sg[2][gi+3], g3y1 = sg[3][gi+3], g3a = sg[4][gi+3];
    u64 t0[4] = {0,0,0,0}, t1[4] = {0,0,0,0}, t2[4] = {0,0,0,0}, t3[4] = {0,0,0,0};
    u32 h0 = 0, h1 = 0, h2 = 0, h3 = 0;
    u32 bit = 1u;
    for (int j = lane; j < acnt; j += 64, bit <<= 1) {
      float4 x = sxy[j];
      float aarea = (x.z - x.x) * (x.w - x.y);
      float v0 = iou_pair(x.x, x.y, x.z, x.w, aarea, g0x0, g0y0, g0x1, g0y1, g0a);
      float v1 = iou_pair(x.x, x.y, x.z, x.w, aarea, g1x0, g1y0, g1x1, g1y1, g1a);
      float v2 = iou_pair(x.x, x.y, x.z, x.w, aarea, g2x0, g2y0, g2x1, g2y1, g2a);
      float v3 = iou_pair(x.x, x.y, x.z, x.w, aarea, g3x0, g3y0, g3x1, g3y1, g3a);
      if (fmaxf(fmaxf(v0, v1), fmaxf(v2, v3)) >= 0.7f) m |= bit;
      u32 ni = ~(u32)(base + j);
      u32 vb0 = __float_as_uint(v0), vb1 = __float_as_uint(v1);
      u32 vb2 = __float_as_uint(v2), vb3 = __float_as_uint(v3);
      if (vb0 >= h0) { top4_insert(t0, ((u64)vb0 << 32) | (u64)ni); h0 = (u32)(t0[3] >> 32); }
      if (vb1 >= h1) { top4_insert(t1, ((u64)vb1 << 32) | (u64)ni); h1 = (u32)(t1[3] >> 32); }
      if (vb2 >= h2) { top4_insert(t2, ((u64)vb2 << 32) | (u64)ni); h2 = (u32)(t2[3] >> 32); }
      if (vb3 >= h3) { top4_insert(t3, ((u64)vb3 << 32) | (u64)ni); h3 = (u32)(t3[3] >> 32); }
    }
    wave_merge_top4(t0);
    wave_merge_top4(t1);
    wave_merge_top4(t2);
    wave_merge_top4(t3);
    if (lane == 0) {
      const int g = half * 32 + gi;
      u64* dst = partial + (((size_t)b * NS + s) * G_N + g) * 4;
      #pragma unroll
      for (int k = 0; k < 4; k++) {
        dst[k] = t0[k]; dst[4 + k] = t1[k]; dst[8 + k] = t2[k]; dst[12 + k] = t3[k];
      }
    }
  }

  wm[t] = m;
  __syncthreads();
  if (wave == 0) {
    u32 mc = wm[lane] | wm[64 + lane] | wm[128 + lane] | wm[192 + lane];
    u64* posH = (half ? posB : posA) + (size_t)b * NWORD + s * WPS;
    for (int k = 0; k < WPS; k++) {
      u64 bal = __ballot((mc >> k) & 1u);
      if (lane == 0) posH[k] = bal;    // plain store — every word covered exactly once
    }
  }
}

// ---------------- Kernel 2: merge -> top4; stripe popcount -> npos; lq -> posA ----------------
__launch_bounds__(64)
__global__ void k_top4_merge(const u64* __restrict__ partial, u64* __restrict__ top4,
                             u64* __restrict__ posA, const u64* __restrict__ posB,
                             u32* __restrict__ npos) {
  const int b = blockIdx.y, g = blockIdx.x, lane = threadIdx.x;

  // stripe popcount of posA|posB -> npos (concurrent lq ORs only undercount ->
  // collect's cutoff only grows -> safe). One atomic per block (512 total).
  {
    const int w0 = g * 49;               // 64 blocks * 49 = 3136 = NWORD
    u32 c = 0;
    if (lane < 49 && w0 + lane < NWORD) {
      u64 w = posA[(size_t)b * NWORD + w0 + lane] | posB[(size_t)b * NWORD + w0 + lane];
      c = (u32)__popcll(w);
    }
    #pragma unroll
    for (int off = 32; off >= 1; off >>= 1) c += __shfl_xor(c, off);
    if (lane == 0 && c) atomicAdd(&npos[b], c);
  }

  const u64* pb = partial + ((size_t)b * NS * G_N + g) * 4;
  u64 keys[7];                           // NS*4 = 392 -> <= 7 per lane
  int nk = 0;
  for (int i = lane; i < NS * 4; i += 64)
    keys[nk++] = pb[(size_t)(i >> 2) * (G_N * 4) + (i & 3)];
  u64 top[4] = {0ull, 0ull, 0ull, 0ull};
  for (int q = 0; q < nk; q++) top4_insert(top, keys[q]);
  wave_merge_top4(top);
  if (lane == 0) {
    u64* dst = top4 + ((size_t)b * G_N + g) * 4;
    #pragma unroll
    for (int k = 0; k < 4; k++) dst[k] = top[k];
  }
  // low-quality matches: every partial entry whose value bits == hq bits.
  u32 hqb = (u32)(__shfl(top[0], 0) >> 32);
  for (int q = 0; q < nk; q++) {
    u64 key = keys[q];
    u32 aidx = ~(u32)key;
    if ((u32)(key >> 32) == hqb && aidx < A_N)
      atomicOr(&posA[(size_t)b * NWORD + (aidx >> 6)], 1ull << (aidx & 63));
  }
}

// ---------------- Kernel 3: cutoff collection, LDS-aggregated ----------------
// grid (NS, B). C = 2^23*2048/max(npos,2048); keys (r23<<18)|a for r23 < C.
// ONE global fetch-add per block (range reservation) — R10/R11's per-candidate
// fetch-adds (~16K to one cacheline across 8 XCDs) were the ~300us tail whale.
__launch_bounds__(256)
__global__ void k_collect(const u64* __restrict__ posA, const u64* __restrict__ posB,
                          const u32* __restrict__ npos,
                          u64* __restrict__ fine, u32* __restrict__ fcnt) {
  const int b = blockIdx.y;
  const int t = threadIdx.x;
  __shared__ u64 lkey[LCAP];
  __shared__ u32 lcnt, lbase;

  if (t == 0) lcnt = 0;
  __syncthreads();

  const u32 np = max(npos[b], 2048u);
  const u32 C = (u32)((((u64)2048u) << 23) / np);   // np=2048 -> 2^23 (keep all)

  u32 k0, k1; image_key(b, k0, k1);
  const int a0 = blockIdx.x * AS;
  const u64* pa = posA + (size_t)b * NWORD;
  const u64* pb = posB + (size_t)b * NWORD;
  for (int j = t; j < AS; j += 256) {
    int a = a0 + j;
    if (a >= A_N) break;
    if (!(((pa[a >> 6] | pb[a >> 6]) >> (a & 63)) & 1ull)) continue;
    u32 r23 = rbits_for(k0, k1, (u32)a) >> 9;
    if (r23 >= C) continue;
    u32 li = atomicAdd(&lcnt, 1u);          // LDS atomic — cheap
    if (li < LCAP) lkey[li] = (((u64)r23) << 18) | (u64)(u32)a;
  }
  __syncthreads();

  const u32 n = min(lcnt, (u32)LCAP);
  if (t == 0 && n) lbase = atomicAdd(&fcnt[b], n);   // ONE global atomic per block
  __syncthreads();
  if (n) {
    const u32 base = lbase;
    for (u32 i = t; i < n; i += 256) {
      u32 idx = base + i;
      if (idx < FINE_CAP) fine[(size_t)b * FINE_CAP + idx] = lkey[i];
    }
  }
}

// ---------------- Kernel 4: threshold + per-gt counts + output (1 block/image) ----------------
__launch_bounds__(256)
__global__ void k_sel(const float4* __restrict__ anchors, const float4* __restrict__ gt,
                      const u64* __restrict__ top4, const u64* __restrict__ fine,
                      const u32* __restrict__ fcnt, float* __restrict__ out, int sec) {
  const int b = blockIdx.x;
  const int t = threadIdx.x;
  __shared__ float sg[5][64];
  __shared__ u32 red[256];
  __shared__ u32 scnt[64];
  __shared__ u64 sT;

  if (t < 64) {
    float x0, y0, x1, y1, ar;
    conv_box(gt[(size_t)b * G_N + t], x0, y0, x1, y1, ar);
    sg[0][t] = x0; sg[1][t] = y0; sg[2][t] = x1; sg[3][t] = y1; sg[4][t] = ar;
    scnt[t] = 0;
  }
  __syncthreads();

  const int m = min((int)fcnt[b], FINE_CAP);
  const u64* fb = fine + (size_t)b * FINE_CAP;

  // exact 128th-smallest threshold over the fine list (keys distinct)
  if (m > MAX_POS) {
    u64 lo = 0, hi = ((u64)1 << 41) - 1;
    while (lo < hi) {
      u64 mid = lo + ((hi - lo) >> 1);
      u32 c = 0;
      for (int j = t; j < m; j += 256) c += (fb[j] <= mid) ? 1u : 0u;
      red[t] = c;
      __syncthreads();
      for (int s = 128; s > 0; s >>= 1) { if (t < s) red[t] += red[t + s]; __syncthreads(); }
      c = red[0];
      __syncthreads();
      if (c >= MAX_POS) hi = mid; else lo = mid + 1;   // uniform
    }
    if (t == 0) sT = lo;
  } else if (t == 0) sT = ~0ull;
  __syncthreads();

  // argmax-gt for each selected anchor (<=128), LDS counts
  const u64 T = sT;
  const float4* ab = anchors + (size_t)b * A_N;
  for (int e = t; e < m; e += 256) {
    u64 ke = fb[e];
    if (ke > T) continue;
    u32 a = (u32)(ke & 0x3FFFFu);
    float ax0, ay0, ax1, ay1, aar;
    conv_box(ab[a], ax0, ay0, ax1, ay1, aar);
    float bv = -1.0f; int g0 = 0;
    for (int g = 0; g < 64; g++) {
      float v = iou_pair(ax0, ay0, ax1, ay1, aar,
                         sg[0][g], sg[1][g], sg[2][g], sg[3][g], sg[4][g]);
      if (v > bv) { bv = v; g0 = g; }   // strict > = first max (jnp.argmax)
    }
    atomicAdd(&scnt[g0], 1u);
  }
  __syncthreads();

  if (t < 64) {
    const int g = t;
    const u32 c = min(scnt[g], (u32)K_TOP);
    const u64* t4 = top4 + ((size_t)b * G_N + g) * 4;
    #pragma unroll
    for (int k = 0; k < 4; k++) {
      u64 key = t4[k];
      u32 fbits = (u32)(key >> 32);
      u32 aidx = ~(u32)key;
      bool valid = (u32)k < c;
      int o = b * (G_N * K_TOP) + g * K_TOP + k;
      out[0 * sec + o] = valid ? (float)aidx : -1.0f;             // pr_inds
      out[1 * sec + o] = valid ? (float)g : -1.0f;                // gt_inds
      out[2 * sec + o] = valid ? 1.0f : 0.0f;                     // valid mask
      out[3 * sec + o] = valid ? __uint_as_float(fbits) : 0.0f;   // topk ious
    }
  }
}

extern "C" void kernel_launch(void* const* d_in, const int* in_sizes, int n_in,
                              void* d_out, int out_size, void* d_ws, size_t ws_size,
                              hipStream_t stream) {
  const float4* anchors = (const float4*)d_in[0];  // [B, A, 4] cxcywh
  const float4* gt      = (const float4*)d_in[1];  // [B, G, 4] cxcywh
  float* out = (float*)d_out;                      // 4 x [B, G*K] concatenated

  // Layout — IDENTICAL EXTENT to the proven 2,025,536 B:
  //   top4    @ 0          (16,384)
  //   partial @ 16,384     (1,605,632) — dead after k_top4_merge; aliased by:
  //       fine @ 16,384      (8192*8*8 = 524,288)  [k_collect, post-merge]
  //   posA    @ 1,622,016  (200,704)  [fully ballot-stored — no init]
  //   posB    @ 1,822,720  (200,704)  [fully ballot-stored — no init]
  //   small   @ 2,023,424  (64): npos(32) fcnt(32) [zeroed by k_top4_part s==0]
  char* ws = (char*)d_ws;
  u64*  top4    = (u64*)(ws);
  u64*  partial = (u64*)(ws + 16384);
  u64*  fine    = (u64*)(ws + 16384);
  u64*  posA    = (u64*)(ws + 1622016);
  u64*  posB    = (u64*)(ws + 1822720);
  u32*  npos    = (u32*)(ws + 2023424);
  u32*  fcnt    = (u32*)(ws + 2023456);

  int sec = out_size / 4;  // 2048 = B*G*K

  k_top4_part <<<dim3(NS, B_IMG * 2), 256, 0, stream>>>(anchors, gt, partial, posA, posB,
                                                        npos, fcnt);
  k_top4_merge<<<dim3(G_N, B_IMG), 64, 0, stream>>>(partial, top4, posA, posB, npos);
  k_collect   <<<dim3(NS, B_IMG), 256, 0, stream>>>(posA, posB, npos, fine, fcnt);
  k_sel       <<<dim3(B_IMG), 256, 0, stream>>>(anchors, gt, top4, fine, fcnt, out, sec);
}